// Round 1
// baseline (109.780 us; speedup 1.0000x reference)
//
#include <hip/hip_runtime.h>
#include <math.h>

#define N_PTS 8192
#define K_CMP 128
#define D_DIM 128
#define NT    128      // n rows per main-kernel block
#define LDST  136      // padded LDS row stride (bf16 elems): 2-way bank alias = free

typedef __attribute__((ext_vector_type(8))) short  short8;   // 8 x bf16 (4 VGPR)
typedef __attribute__((ext_vector_type(8))) unsigned short ushort8;
typedef __attribute__((ext_vector_type(4))) unsigned short ushort4v;
typedef __attribute__((ext_vector_type(4))) float  f32x4;

static __device__ __forceinline__ unsigned short f2bf(float f) {
    union { float f; unsigned u; } v; v.f = f;
    unsigned r = v.u + 0x7fffu + ((v.u >> 16) & 1u);   // RNE
    return (unsigned short)(r >> 16);
}
static __device__ __forceinline__ float bf2f(unsigned short h) {
    union { unsigned u; float f; } v; v.u = ((unsigned)h) << 16;
    return v.f;
}

// ---------------- prep: cvec[k] = logdet[k] + log_softmax(weigh)[k] ----------
__global__ void prep_const(const float* __restrict__ logvar,
                           const float* __restrict__ weigh,
                           float* __restrict__ cvec) {
    int k = threadIdx.x;              // 128 threads, 1 block
    float ld = 0.f;
    for (int d = 0; d < D_DIM; ++d) {
        float v = expf(logvar[k * D_DIM + d]);
        ld += logf(fabsf(v) + 1e-8f);
    }
    __shared__ float red[K_CMP];
    float wk = weigh[k];
    red[k] = wk;
    __syncthreads();
    float m = red[0];
    for (int i = 1; i < K_CMP; ++i) m = fmaxf(m, red[i]);
    float s = 0.f;
    for (int i = 0; i < K_CMP; ++i) s += expf(red[i] - m);
    cvec[k] = ld + (wk - m - logf(s));
}

// ---------------- prep: x (fp32) -> xb (bf16) --------------------------------
__global__ void prep_xb(const float* __restrict__ x, unsigned short* __restrict__ xb) {
    int i = blockIdx.x * blockDim.x + threadIdx.x;   // one float4 per thread
    const float4 v = ((const float4*)x)[i];
    ushort4v o;
    o.x = f2bf(v.x); o.y = f2bf(v.y); o.z = f2bf(v.z); o.w = f2bf(v.w);
    *(ushort4v*)&xb[(size_t)i * 4] = o;
}

// ---------------- prep: tri (fp32) -> M_k = I + tril(tri,-1) in bf16 ---------
__global__ void prep_tri(const float* __restrict__ tri, unsigned short* __restrict__ Lb) {
    size_t i4 = (size_t)blockIdx.x * blockDim.x + threadIdx.x; // one float4 per thread
    size_t idx = i4 * 4;
    int d = (int)((idx >> 7) & 127);
    int e0 = (int)(idx & 127);
    const float4 v = ((const float4*)tri)[i4];
    float vals[4] = {v.x, v.y, v.z, v.w};
    ushort4v o;
    #pragma unroll
    for (int j = 0; j < 4; ++j) {
        int e = e0 + j;
        float val = (e < d) ? vals[j] : (e == d ? 1.0f : 0.0f);
        ((unsigned short*)&o)[j] = f2bf(val);
    }
    *(ushort4v*)&Lb[idx] = o;
}

// ---------------- main: per (k, n-tile): logits[k][n] = -0.5*||(I+L)y||^2 + cvec[k]
__launch_bounds__(256, 2)
__global__ void gmm_main(const unsigned short* __restrict__ xb,
                         const unsigned short* __restrict__ Lb,
                         const float* __restrict__ means,
                         const float* __restrict__ logvar,
                         const float* __restrict__ cvec,
                         float* __restrict__ logits) {
    __shared__ unsigned short Ys[NT][LDST];
    __shared__ unsigned short Ls[D_DIM][LDST];
    __shared__ float mean_s[D_DIM];
    __shared__ float var_s[D_DIM];
    __shared__ float qsum[2][NT];

    const int ntiles = N_PTS / NT;               // 64
    const int k  = blockIdx.x / ntiles;          // k-major: consecutive blocks share M_k in L2
    const int t0 = (blockIdx.x % ntiles) * NT;
    const int tid = threadIdx.x;

    if (tid < D_DIM) {
        mean_s[tid] = means[k * D_DIM + tid];
        var_s[tid]  = expf(logvar[k * D_DIM + tid]);
    }

    // stage M_k (bf16) -> LDS, padded stride
    {
        const size_t base = (size_t)k * D_DIM * D_DIM;
        #pragma unroll
        for (int p = 0; p < 8; ++p) {
            int row = p * 16 + (tid >> 4);
            int c8  = (tid & 15) * 8;
            ushort8 v = *(const ushort8*)&Lb[base + (size_t)row * D_DIM + c8];
            *(ushort8*)&Ls[row][c8] = v;
        }
    }
    __syncthreads();   // mean/var + Ls visible

    // stage Y = (x - mu_k) * var_k (bf16) -> LDS
    #pragma unroll
    for (int p = 0; p < (NT / 16); ++p) {
        int row = p * 16 + (tid >> 4);
        int c8  = (tid & 15) * 8;
        ushort8 xv = *(const ushort8*)&xb[(size_t)(t0 + row) * D_DIM + c8];
        ushort8 yv;
        #pragma unroll
        for (int j = 0; j < 8; ++j) {
            float xf = bf2f(((unsigned short*)&xv)[j]);
            float y  = (xf - mean_s[c8 + j]) * var_s[c8 + j];
            ((unsigned short*)&yv)[j] = f2bf(y);
        }
        *(ushort8*)&Ys[row][c8] = yv;
    }
    __syncthreads();

    // MFMA: Z[n][d] = sum_e Y[n][e] * M[d][e]
    const int wave = tid >> 6;
    const int lane = tid & 63;
    const int wr = wave >> 1, wc = wave & 1;       // 2x2 wave grid, 64x64 tiles
    const int lrow = lane & 15;
    const int lk   = (lane >> 4) * 8;

    f32x4 acc[4][4];
    #pragma unroll
    for (int mi = 0; mi < 4; ++mi)
        #pragma unroll
        for (int nj = 0; nj < 4; ++nj)
            acc[mi][nj] = (f32x4){0.f, 0.f, 0.f, 0.f};

    #pragma unroll
    for (int s = 0; s < 4; ++s) {
        const int e = s * 32 + lk;
        short8 a[4], b[4];
        #pragma unroll
        for (int mi = 0; mi < 4; ++mi)
            a[mi] = *(const short8*)&Ys[wr * 64 + mi * 16 + lrow][e];
        #pragma unroll
        for (int nj = 0; nj < 4; ++nj)
            b[nj] = *(const short8*)&Ls[wc * 64 + nj * 16 + lrow][e];
        #pragma unroll
        for (int mi = 0; mi < 4; ++mi)
            #pragma unroll
            for (int nj = 0; nj < 4; ++nj)
                acc[mi][nj] = __builtin_amdgcn_mfma_f32_16x16x32_bf16(
                    a[mi], b[nj], acc[mi][nj], 0, 0, 0);
    }

    // quad row-sums: C/D layout col=lane&15, row=(lane>>4)*4+reg
    #pragma unroll
    for (int mi = 0; mi < 4; ++mi) {
        float p0 = 0.f, p1 = 0.f, p2 = 0.f, p3 = 0.f;
        #pragma unroll
        for (int nj = 0; nj < 4; ++nj) {
            f32x4 z = acc[mi][nj];
            p0 += z.x * z.x; p1 += z.y * z.y; p2 += z.z * z.z; p3 += z.w * z.w;
        }
        #pragma unroll
        for (int off = 1; off < 16; off <<= 1) {
            p0 += __shfl_xor(p0, off, 64);
            p1 += __shfl_xor(p1, off, 64);
            p2 += __shfl_xor(p2, off, 64);
            p3 += __shfl_xor(p3, off, 64);
        }
        if (lrow == 0) {
            int rb = wr * 64 + mi * 16 + (lane >> 4) * 4;
            qsum[wc][rb + 0] = p0;
            qsum[wc][rb + 1] = p1;
            qsum[wc][rb + 2] = p2;
            qsum[wc][rb + 3] = p3;
        }
    }
    __syncthreads();

    if (tid < NT) {
        float q = qsum[0][tid] + qsum[1][tid];
        logits[(size_t)k * N_PTS + t0 + tid] = -0.5f * q + cvec[k];
    }
}

// ---------------- lse: out[n] = -(logC + logsumexp_k logits[k][n]) -----------
__global__ void lse_kernel(const float* __restrict__ logits, float* __restrict__ out) {
    int n = blockIdx.x * blockDim.x + threadIdx.x;
    float m = -INFINITY, s = 0.f;
    for (int k = 0; k < K_CMP; ++k) {
        float v = logits[(size_t)k * N_PTS + n];
        float nm = fmaxf(m, v);
        s = s * __expf(m - nm) + __expf(v - nm);
        m = nm;
    }
    const float logC = -117.62413225f;   // -0.5 * 128 * log(2*pi)
    out[n] = -(logC + m + logf(s));
}

extern "C" void kernel_launch(void* const* d_in, const int* in_sizes, int n_in,
                              void* d_out, int out_size, void* d_ws, size_t ws_size,
                              hipStream_t stream) {
    const float* x      = (const float*)d_in[0];   // [N, D]
    const float* means  = (const float*)d_in[1];   // [K, D]
    const float* logvar = (const float*)d_in[2];   // [1, K, D]
    const float* tri    = (const float*)d_in[3];   // [1, K, D, D]
    const float* weigh  = (const float*)d_in[4];   // [1, K]
    float* out = (float*)d_out;                    // [N, 1]

    // workspace layout
    unsigned char* ws = (unsigned char*)d_ws;
    unsigned short* Lb   = (unsigned short*)(ws);                         // 4 MB: K*D*D bf16
    unsigned short* xbuf = (unsigned short*)(ws + (size_t)4 * 1024 * 1024);   // 2 MB: N*D bf16
    float*          cvec = (float*)(ws + (size_t)6 * 1024 * 1024);            // 512 B
    float*          logits = (float*)(ws + (size_t)6 * 1024 * 1024 + 4096);   // 4 MB: [K][N]

    hipLaunchKernelGGL(prep_tri, dim3((K_CMP * D_DIM * D_DIM / 4) / 256), dim3(256), 0, stream,
                       tri, Lb);
    hipLaunchKernelGGL(prep_xb, dim3((N_PTS * D_DIM / 4) / 256), dim3(256), 0, stream,
                       x, xbuf);
    hipLaunchKernelGGL(prep_const, dim3(1), dim3(128), 0, stream, logvar, weigh, cvec);

    hipLaunchKernelGGL(gmm_main, dim3(K_CMP * (N_PTS / NT)), dim3(256), 0, stream,
                       xbuf, Lb, means, logvar, cvec, logits);

    hipLaunchKernelGGL(lse_kernel, dim3(N_PTS / 256), dim3(256), 0, stream, logits, out);
}

// Round 2
// 85.092 us; speedup vs baseline: 1.2901x; 1.2901x over previous
//
#include <hip/hip_runtime.h>
#include <math.h>

#define N_PTS 8192
#define K_CMP 128
#define D_DIM 128
#define NT    128      // n rows per main-kernel block

typedef __attribute__((ext_vector_type(8))) short  short8;   // 8 x bf16
typedef __attribute__((ext_vector_type(8))) unsigned short ushort8;
typedef __attribute__((ext_vector_type(4))) unsigned short ushort4v;
typedef __attribute__((ext_vector_type(4))) float  f32x4;

static __device__ __forceinline__ unsigned short f2bf(float f) {
    union { float f; unsigned u; } v; v.f = f;
    unsigned r = v.u + 0x7fffu + ((v.u >> 16) & 1u);   // RNE
    return (unsigned short)(r >> 16);
}
static __device__ __forceinline__ float bf2f(unsigned short h) {
    union { unsigned u; float f; } v; v.u = ((unsigned)h) << 16;
    return v.f;
}

// ---------------- prep: cvec[k] = logdet[k] + log_softmax(weigh)[k] ----------
__global__ void prep_const(const float* __restrict__ logvar,
                           const float* __restrict__ weigh,
                           float* __restrict__ cvec) {
    int k = threadIdx.x;              // 128 threads, 1 block
    float ld = 0.f;
    for (int d = 0; d < D_DIM; ++d) {
        float v = expf(logvar[k * D_DIM + d]);
        ld += logf(fabsf(v) + 1e-8f);
    }
    __shared__ float red[K_CMP];
    float wk = weigh[k];
    red[k] = wk;
    __syncthreads();
    float m = red[0];
    for (int i = 1; i < K_CMP; ++i) m = fmaxf(m, red[i]);
    float s = 0.f;
    for (int i = 0; i < K_CMP; ++i) s += expf(red[i] - m);
    cvec[k] = ld + (wk - m - logf(s));
}

// ---------------- prep: x (fp32) -> xb (bf16) --------------------------------
__global__ void prep_xb(const float* __restrict__ x, unsigned short* __restrict__ xb) {
    int i = blockIdx.x * blockDim.x + threadIdx.x;   // one float4 per thread
    const float4 v = ((const float4*)x)[i];
    ushort4v o;
    o.x = f2bf(v.x); o.y = f2bf(v.y); o.z = f2bf(v.z); o.w = f2bf(v.w);
    *(ushort4v*)&xb[(size_t)i * 4] = o;
}

// ---------------- prep: M'_k = (I + tril(tri,-1)) * diag(var_k) in bf16,
//                  c_k[d] = sum_e M'b[d][e] * mu_k[e]  (fp32) -----------------
__global__ void prep_M(const float* __restrict__ tri,
                       const float* __restrict__ logvar,
                       const float* __restrict__ means,
                       unsigned short* __restrict__ Mb,
                       float* __restrict__ cv) {
    const int k = blockIdx.x;                  // 128 blocks, 256 threads
    __shared__ float var_s[D_DIM], mu_s[D_DIM];
    const int tid = threadIdx.x;
    if (tid < D_DIM) {
        var_s[tid] = expf(logvar[k * D_DIM + tid]);
        mu_s[tid]  = means[k * D_DIM + tid];
    }
    __syncthreads();
    const int wave = tid >> 6, lane = tid & 63;
    const size_t kb = (size_t)k * D_DIM * D_DIM;
    #pragma unroll
    for (int i = 0; i < 8; ++i) {
        const int r = wave * 32 + i * 4 + (lane >> 4);   // row (d)
        const int p = lane & 15;                         // 16B chunk
        const int e = p * 8;
        const float4 v0 = *(const float4*)&tri[kb + (size_t)r * D_DIM + e];
        const float4 v1 = *(const float4*)&tri[kb + (size_t)r * D_DIM + e + 4];
        const float vals[8] = {v0.x, v0.y, v0.z, v0.w, v1.x, v1.y, v1.z, v1.w};
        ushort8 ob;
        float cacc = 0.f;
        #pragma unroll
        for (int j = 0; j < 8; ++j) {
            const int ee = e + j;
            float val = (ee < r) ? vals[j] * var_s[ee] : (ee == r ? var_s[r] : 0.f);
            unsigned short b = f2bf(val);
            ((unsigned short*)&ob)[j] = b;
            cacc = fmaf(bf2f(b), mu_s[ee], cacc);
        }
        *(ushort8*)&Mb[kb + (size_t)r * D_DIM + e] = ob;
        cacc += __shfl_xor(cacc, 1, 64);
        cacc += __shfl_xor(cacc, 2, 64);
        cacc += __shfl_xor(cacc, 4, 64);
        cacc += __shfl_xor(cacc, 8, 64);
        if (p == 0) cv[k * D_DIM + r] = cacc;
    }
}

// ---------------- main: logits[k][n] = -0.5*||M'_k xb[n] - c_k||^2 + cvec[k] --
// A = M' (rows = d), B = Xb (rows = n); acc initialized to -c so MFMA output
// is already (z - c). LDS uses 16B-chunk XOR swizzle: chunk ^ (row & 7).
__launch_bounds__(256, 2)
__global__ void gmm_main(const unsigned short* __restrict__ xb,
                         const unsigned short* __restrict__ Mb,
                         const float* __restrict__ cv,
                         const float* __restrict__ cvec,
                         float* __restrict__ logits) {
    __shared__ unsigned short Ms[D_DIM][D_DIM];
    __shared__ unsigned short Xs[NT][D_DIM];
    __shared__ float qsum[2][NT];

    const int ntiles = N_PTS / NT;               // 64; k-major for M' L2 reuse
    const int k  = blockIdx.x / ntiles;
    const int t0 = (blockIdx.x % ntiles) * NT;
    const int tid  = threadIdx.x;
    const int wave = tid >> 6, lane = tid & 63;

    // ---- stage M' and X tiles (pure bf16 copies, swizzled LDS writes) ----
    {
        const unsigned short* Mg = Mb + (size_t)k  * D_DIM * D_DIM;
        const unsigned short* Xg = xb + (size_t)t0 * D_DIM;
        const int rbase = wave * 32;
        #pragma unroll
        for (int i = 0; i < 8; ++i) {
            const int r  = rbase + i * 4 + (lane >> 4);
            const int p  = lane & 15;
            const int sw = (p ^ (r & 7)) * 8;
            const ushort8 mv = *(const ushort8*)&Mg[(size_t)r * D_DIM + p * 8];
            const ushort8 xv = *(const ushort8*)&Xg[(size_t)r * D_DIM + p * 8];
            *(ushort8*)&Ms[r][sw] = mv;
            *(ushort8*)&Xs[r][sw] = xv;
        }
    }

    // ---- acc init = -c (folds the mean subtraction into MFMA) ----
    const int wd = wave >> 1, wn = wave & 1;     // 2x2 wave grid: 64d x 64n
    const int lrow = lane & 15;
    const int lkg  = lane >> 4;                  // 0..3

    f32x4 acc[4][4];                             // [di][nj]
    {
        const float* cp = cv + k * D_DIM + wd * 64;
        #pragma unroll
        for (int di = 0; di < 4; ++di) {
            const float c0 = cp[di * 16 + lkg * 4 + 0];
            const float c1 = cp[di * 16 + lkg * 4 + 1];
            const float c2 = cp[di * 16 + lkg * 4 + 2];
            const float c3 = cp[di * 16 + lkg * 4 + 3];
            #pragma unroll
            for (int nj = 0; nj < 4; ++nj)
                acc[di][nj] = (f32x4){-c0, -c1, -c2, -c3};
        }
    }
    __syncthreads();

    // ---- MFMA: Z[d][n] = sum_e M'[d][e] * Xb[n][e], acc starts at -c ----
    #pragma unroll
    for (int s = 0; s < 4; ++s) {
        short8 a[4], b[4];
        #pragma unroll
        for (int di = 0; di < 4; ++di) {
            const int r  = wd * 64 + di * 16 + lrow;
            const int ch = (s * 4 + lkg) ^ (r & 7);
            a[di] = *(const short8*)&Ms[r][ch * 8];
        }
        #pragma unroll
        for (int nj = 0; nj < 4; ++nj) {
            const int r  = wn * 64 + nj * 16 + lrow;
            const int ch = (s * 4 + lkg) ^ (r & 7);
            b[nj] = *(const short8*)&Xs[r][ch * 8];
        }
        #pragma unroll
        for (int di = 0; di < 4; ++di)
            #pragma unroll
            for (int nj = 0; nj < 4; ++nj)
                acc[di][nj] = __builtin_amdgcn_mfma_f32_16x16x32_bf16(
                    a[di], b[nj], acc[di][nj], 0, 0, 0);
    }

    // ---- epilogue: q[n] = sum_d t^2; d-reduction is mostly lane-local ----
    // C/D layout: col(lane&15)=n (B rows), row((lane>>4)*4+reg)=d (A rows)
    float q[4];
    #pragma unroll
    for (int nj = 0; nj < 4; ++nj) {
        float p = 0.f;
        #pragma unroll
        for (int di = 0; di < 4; ++di) {
            const f32x4 z = acc[di][nj];
            p += z.x * z.x; p += z.y * z.y; p += z.z * z.z; p += z.w * z.w;
        }
        p += __shfl_xor(p, 16, 64);
        p += __shfl_xor(p, 32, 64);
        q[nj] = p;
    }
    if (lane < 16) {
        #pragma unroll
        for (int nj = 0; nj < 4; ++nj)
            qsum[wd][wn * 64 + nj * 16 + lane] = q[nj];
    }
    __syncthreads();

    if (tid < NT) {
        const float qq = qsum[0][tid] + qsum[1][tid];
        logits[(size_t)k * N_PTS + t0 + tid] = -0.5f * qq + cvec[k];
    }
}

// ---------------- lse: out[n] = -(logC + logsumexp_k logits[k][n]) -----------
__global__ void lse_kernel(const float* __restrict__ logits, float* __restrict__ out) {
    const int n = blockIdx.x * blockDim.x + threadIdx.x;
    float m0 = -INFINITY, m1 = -INFINITY, m2 = -INFINITY, m3 = -INFINITY;
    float s0 = 0.f, s1 = 0.f, s2 = 0.f, s3 = 0.f;
    for (int k = 0; k < K_CMP; k += 4) {
        const float v0 = logits[(size_t)(k + 0) * N_PTS + n];
        const float v1 = logits[(size_t)(k + 1) * N_PTS + n];
        const float v2 = logits[(size_t)(k + 2) * N_PTS + n];
        const float v3 = logits[(size_t)(k + 3) * N_PTS + n];
        float nm;
        nm = fmaxf(m0, v0); s0 = s0 * __expf(m0 - nm) + __expf(v0 - nm); m0 = nm;
        nm = fmaxf(m1, v1); s1 = s1 * __expf(m1 - nm) + __expf(v1 - nm); m1 = nm;
        nm = fmaxf(m2, v2); s2 = s2 * __expf(m2 - nm) + __expf(v2 - nm); m2 = nm;
        nm = fmaxf(m3, v3); s3 = s3 * __expf(m3 - nm) + __expf(v3 - nm); m3 = nm;
    }
    const float m = fmaxf(fmaxf(m0, m1), fmaxf(m2, m3));
    const float s = s0 * __expf(m0 - m) + s1 * __expf(m1 - m) +
                    s2 * __expf(m2 - m) + s3 * __expf(m3 - m);
    const float logC = -117.62413225f;   // -0.5 * 128 * log(2*pi)
    out[n] = -(logC + m + logf(s));
}

extern "C" void kernel_launch(void* const* d_in, const int* in_sizes, int n_in,
                              void* d_out, int out_size, void* d_ws, size_t ws_size,
                              hipStream_t stream) {
    const float* x      = (const float*)d_in[0];   // [N, D]
    const float* means  = (const float*)d_in[1];   // [K, D]
    const float* logvar = (const float*)d_in[2];   // [1, K, D]
    const float* tri    = (const float*)d_in[3];   // [1, K, D, D]
    const float* weigh  = (const float*)d_in[4];   // [1, K]
    float* out = (float*)d_out;                    // [N, 1]

    // workspace layout
    unsigned char* ws = (unsigned char*)d_ws;
    unsigned short* Mb   = (unsigned short*)(ws);                              // 4 MB: K*D*D bf16
    unsigned short* xbuf = (unsigned short*)(ws + (size_t)4 * 1024 * 1024);    // 2 MB: N*D bf16
    float*          cv   = (float*)(ws + (size_t)6 * 1024 * 1024);             // 64 KB: c[K][D]
    float*          cvec = (float*)(ws + (size_t)6 * 1024 * 1024 + 65536);     // 512 B
    float*          logits = (float*)(ws + (size_t)6 * 1024 * 1024 + 131072);  // 4 MB: [K][N]

    hipLaunchKernelGGL(prep_M, dim3(K_CMP), dim3(256), 0, stream,
                       tri, logvar, means, Mb, cv);
    hipLaunchKernelGGL(prep_xb, dim3((N_PTS * D_DIM / 4) / 256), dim3(256), 0, stream,
                       x, xbuf);
    hipLaunchKernelGGL(prep_const, dim3(1), dim3(128), 0, stream, logvar, weigh, cvec);

    hipLaunchKernelGGL(gmm_main, dim3(K_CMP * (N_PTS / NT)), dim3(256), 0, stream,
                       xbuf, Mb, cv, cvec, logits);

    hipLaunchKernelGGL(lse_kernel, dim3(N_PTS / 128), dim3(128), 0, stream, logits, out);
}